// Round 1
// baseline (78.941 us; speedup 1.0000x reference)
//
#include <hip/hip_runtime.h>

// Problem dims (fixed by setup_inputs): B=4, S=1024, T=256, H=512, A=256
#define B_ 4
#define S_ 1024
#define T_ 256
#define H_ 512
#define A_ 256
#define TT 4   // t-rows per score block

__device__ __forceinline__ float ex2(float x) { return __builtin_amdgcn_exp2f(x); }
__device__ __forceinline__ float rcpf_(float x) { return __builtin_amdgcn_rcpf(x); }

// 2*log2(e): exp(2x) = exp2(K2F * x)
#define K2F 2.8853900817779268f
#define LOG2EF 1.4426950408889634f

// ---------------------------------------------------------------------------
// Kernel 1: fused GEMM + exp epilogue.
//   blocks [0,256):   E[b][a][s] = exp(2*(enc@Wh + bh))   (TRANSPOSED store)
//   blocks [256,320): D[m][a]    = exp(2*(dec@Ws + bs))   (row-major store)
// 64x64 tile, 256 threads, 4x4 per thread, K-step 16.
// ---------------------------------------------------------------------------
__global__ __launch_bounds__(256)
void fused_gemm_exp(const float* __restrict__ enc, const float* __restrict__ dec,
                    const float* __restrict__ Wh,  const float* __restrict__ bh,
                    const float* __restrict__ Wsm, const float* __restrict__ bs,
                    float* __restrict__ Ebuf, float* __restrict__ Dbuf)
{
    __shared__ float As[16][64];   // A tile, transposed: As[k][m]
    __shared__ float Bs[16][64];   // W tile: Bs[k][n]

    const int tid = threadIdx.x;
    const int bid = blockIdx.x;
    const bool isE = (bid < 256);

    const float* Am; const float* Wm; const float* bi;
    int mb, nb;
    if (isE) { mb = (bid & 63) << 6;  nb = (bid >> 6) << 6; Am = enc; Wm = Wh;  bi = bh; }
    else     { int b2 = bid - 256; mb = (b2 & 15) << 6; nb = (b2 >> 4) << 6; Am = dec; Wm = Wsm; bi = bs; }

    const int ar = tid >> 2, ak = (tid & 3) << 2;    // A-tile load: row, k-col
    const int wr = tid >> 4, wn = (tid & 15) << 2;   // W-tile load: k-row, n-col
    const int m0 = (tid & 15) << 2, n0 = (tid >> 4) << 2;  // output sub-tile

    float c[4][4] = {};

    for (int k0 = 0; k0 < H_; k0 += 16) {
        float4 av = *(const float4*)&Am[(size_t)(mb + ar) * H_ + k0 + ak];
        float4 wv = *(const float4*)&Wm[(size_t)(k0 + wr) * A_ + nb + wn];
        __syncthreads();   // previous iter's reads done before overwrite
        As[ak + 0][ar] = av.x; As[ak + 1][ar] = av.y;
        As[ak + 2][ar] = av.z; As[ak + 3][ar] = av.w;
        *(float4*)&Bs[wr][wn] = wv;
        __syncthreads();
        #pragma unroll
        for (int kk = 0; kk < 16; ++kk) {
            float4 a4 = *(const float4*)&As[kk][m0];
            float4 b4 = *(const float4*)&Bs[kk][n0];
            c[0][0] = fmaf(a4.x, b4.x, c[0][0]); c[0][1] = fmaf(a4.x, b4.y, c[0][1]);
            c[0][2] = fmaf(a4.x, b4.z, c[0][2]); c[0][3] = fmaf(a4.x, b4.w, c[0][3]);
            c[1][0] = fmaf(a4.y, b4.x, c[1][0]); c[1][1] = fmaf(a4.y, b4.y, c[1][1]);
            c[1][2] = fmaf(a4.y, b4.z, c[1][2]); c[1][3] = fmaf(a4.y, b4.w, c[1][3]);
            c[2][0] = fmaf(a4.z, b4.x, c[2][0]); c[2][1] = fmaf(a4.z, b4.y, c[2][1]);
            c[2][2] = fmaf(a4.z, b4.z, c[2][2]); c[2][3] = fmaf(a4.z, b4.w, c[2][3]);
            c[3][0] = fmaf(a4.w, b4.x, c[3][0]); c[3][1] = fmaf(a4.w, b4.y, c[3][1]);
            c[3][2] = fmaf(a4.w, b4.z, c[3][2]); c[3][3] = fmaf(a4.w, b4.w, c[3][3]);
        }
    }

    // epilogue: e = exp(2*(c + bias)) = exp2(K2F*(c+bias))
    float4 bv4 = *(const float4*)&bi[nb + n0];
    float bb[4] = {bv4.x, bv4.y, bv4.z, bv4.w};
    float e[4][4];
    #pragma unroll
    for (int i = 0; i < 4; ++i)
        #pragma unroll
        for (int j = 0; j < 4; ++j)
            e[i][j] = ex2((c[i][j] + bb[j]) * K2F);

    if (isE) {
        // transposed store: Ebuf[b][a][s], tile lies within one batch (S%64==0)
        const int b = mb >> 10;             // mb / 1024
        const int s = (mb & 1023) + m0;
        #pragma unroll
        for (int j = 0; j < 4; ++j) {
            float4 v = make_float4(e[0][j], e[1][j], e[2][j], e[3][j]);
            *(float4*)&Ebuf[((size_t)b * A_ + (nb + n0 + j)) * S_ + s] = v;
        }
    } else {
        #pragma unroll
        for (int i = 0; i < 4; ++i) {
            float4 v = make_float4(e[i][0], e[i][1], e[i][2], e[i][3]);
            *(float4*)&Dbuf[(size_t)(mb + m0 + i) * A_ + nb + n0] = v;
        }
    }
}

// ---------------------------------------------------------------------------
// Kernel 2: fused score + softmax.
// block = (b, 4 t-rows); 256 threads, each owns 4 consecutive s (full S=1024).
// score'[t][s] = -2 * sum_a Wv[a] / (E[b,a,s]*D[b,t,a] + 1)
// (constant shifts sum(Wv) and bv cancel under softmax)
// ---------------------------------------------------------------------------
__global__ __launch_bounds__(256)
void score_softmax(const float* __restrict__ E, const float* __restrict__ D,
                   const float* __restrict__ Wv, float* __restrict__ out)
{
    const int tid = threadIdx.x;
    const int b  = blockIdx.x >> 6;          // / (T_/TT) = 64
    const int t0 = (blockIdx.x & 63) * TT;

    __shared__ float dsh[TT][A_];
    __shared__ float wsh[A_];
    __shared__ float red[TT][4];

    {
        int r = tid >> 6, c4 = (tid & 63) << 2;
        *(float4*)&dsh[r][c4] = *(const float4*)&D[((size_t)b * T_ + t0 + r) * A_ + c4];
        if (tid < 64) *(float4*)&wsh[tid << 2] = *(const float4*)&Wv[tid << 2];
    }
    __syncthreads();

    const int s0 = tid << 2;
    const float* Eb = E + (size_t)b * A_ * S_ + s0;

    float acc[TT][4] = {};
    float4 eA[8], eB[8];
    #pragma unroll
    for (int u = 0; u < 8; ++u) eA[u] = *(const float4*)&Eb[(size_t)u * S_];

#define COMPUTE_HALF(EV, ABASE)                                                  \
    {                                                                            \
        float wl[8];                                                             \
        _Pragma("unroll")                                                        \
        for (int u = 0; u < 8; ++u) wl[u] = wsh[(ABASE) + u];                    \
        _Pragma("unroll")                                                        \
        for (int t = 0; t < TT; ++t) {                                           \
            _Pragma("unroll")                                                    \
            for (int u = 0; u < 8; ++u) {                                        \
                float d = dsh[t][(ABASE) + u];                                   \
                float w = wl[u];                                                 \
                acc[t][0] = fmaf(w, rcpf_(fmaf(EV[u].x, d, 1.0f)), acc[t][0]);   \
                acc[t][1] = fmaf(w, rcpf_(fmaf(EV[u].y, d, 1.0f)), acc[t][1]);   \
                acc[t][2] = fmaf(w, rcpf_(fmaf(EV[u].z, d, 1.0f)), acc[t][2]);   \
                acc[t][3] = fmaf(w, rcpf_(fmaf(EV[u].w, d, 1.0f)), acc[t][3]);   \
            }                                                                    \
        }                                                                        \
    }

    for (int a0 = 0; a0 < A_; a0 += 16) {
        #pragma unroll
        for (int u = 0; u < 8; ++u) eB[u] = *(const float4*)&Eb[(size_t)(a0 + 8 + u) * S_];
        COMPUTE_HALF(eA, a0);
        if (a0 + 16 < A_) {
            #pragma unroll
            for (int u = 0; u < 8; ++u) eA[u] = *(const float4*)&Eb[(size_t)(a0 + 16 + u) * S_];
        }
        COMPUTE_HALF(eB, a0 + 8);
    }
#undef COMPUTE_HALF

    // ---- softmax over s (per t row) ----
    const int lane = tid & 63, wid = tid >> 6;
    float sc[TT][4];
    #pragma unroll
    for (int t = 0; t < TT; ++t)
        #pragma unroll
        for (int j = 0; j < 4; ++j)
            sc[t][j] = -2.0f * acc[t][j];

    // row max
    #pragma unroll
    for (int t = 0; t < TT; ++t) {
        float mx = fmaxf(fmaxf(sc[t][0], sc[t][1]), fmaxf(sc[t][2], sc[t][3]));
        #pragma unroll
        for (int off = 32; off > 0; off >>= 1) mx = fmaxf(mx, __shfl_xor(mx, off, 64));
        if (lane == 0) red[t][wid] = mx;
    }
    __syncthreads();
    float mrow[TT];
    #pragma unroll
    for (int t = 0; t < TT; ++t)
        mrow[t] = fmaxf(fmaxf(red[t][0], red[t][1]), fmaxf(red[t][2], red[t][3]));
    __syncthreads();

    // exp + row sum
    #pragma unroll
    for (int t = 0; t < TT; ++t) {
        float s = 0.0f;
        #pragma unroll
        for (int j = 0; j < 4; ++j) {
            sc[t][j] = ex2((sc[t][j] - mrow[t]) * LOG2EF);
            s += sc[t][j];
        }
        #pragma unroll
        for (int off = 32; off > 0; off >>= 1) s += __shfl_xor(s, off, 64);
        if (lane == 0) red[t][wid] = s;
    }
    __syncthreads();

    #pragma unroll
    for (int t = 0; t < TT; ++t) {
        float ssum = red[t][0] + red[t][1] + red[t][2] + red[t][3];
        float inv = 1.0f / ssum;
        float4 o = make_float4(sc[t][0] * inv, sc[t][1] * inv, sc[t][2] * inv, sc[t][3] * inv);
        *(float4*)&out[((size_t)b * T_ + (t0 + t)) * S_ + s0] = o;
    }
}

// ---------------------------------------------------------------------------
extern "C" void kernel_launch(void* const* d_in, const int* in_sizes, int n_in,
                              void* d_out, int out_size, void* d_ws, size_t ws_size,
                              hipStream_t stream)
{
    const float* enc = (const float*)d_in[0];
    const float* dec = (const float*)d_in[1];
    const float* Wh  = (const float*)d_in[2];
    const float* bh  = (const float*)d_in[3];
    const float* Wsm = (const float*)d_in[4];
    const float* bs  = (const float*)d_in[5];
    const float* Wv  = (const float*)d_in[6];
    // d_in[7] (bv) intentionally unused: softmax is shift-invariant.

    float* Ebuf = (float*)d_ws;                      // B*A*S floats = 4 MB
    float* Dbuf = Ebuf + (size_t)B_ * A_ * S_;       // B*T*A floats = 1 MB

    fused_gemm_exp<<<320, 256, 0, stream>>>(enc, dec, Wh, bh, Wsm, bs, Ebuf, Dbuf);
    score_softmax<<<B_ * (T_ / TT), 256, 0, stream>>>(Ebuf, Dbuf, Wv, (float*)d_out);
}

// Round 2
// 69.849 us; speedup vs baseline: 1.1302x; 1.1302x over previous
//
#include <hip/hip_runtime.h>

// Problem dims (fixed by setup_inputs): B=4, S=1024, T=256, H=512, A=256
#define B_ 4
#define S_ 1024
#define T_ 256
#define H_ 512
#define A_ 256
#define TT 4   // t-rows per score block

__device__ __forceinline__ float ex2(float x) { return __builtin_amdgcn_exp2f(x); }
__device__ __forceinline__ float rcpf_(float x) { return __builtin_amdgcn_rcpf(x); }

// 2*log2(e): exp(2x) = exp2(K2F * x)
#define K2F 2.8853900817779268f
#define LOG2EF 1.4426950408889634f

// ---------------------------------------------------------------------------
// Kernel 1: fused GEMM + exp epilogue. 64x32 tiles, 256 thr, 4x2/thread.
//   blocks [0,512):   E[b][a][s] = exp(2*(enc@Wh + bh))   (TRANSPOSED store)
//   blocks [512,640): D[m][a]    = exp(2*(dec@Ws + bs))   (row-major store)
// Global loads for K-panel k+16 are issued BEFORE computing panel k
// (latency hidden under FMAs). LDS padded to kill write bank conflicts.
// ---------------------------------------------------------------------------
__global__ __launch_bounds__(256)
void fused_gemm_exp(const float* __restrict__ enc, const float* __restrict__ dec,
                    const float* __restrict__ Wh,  const float* __restrict__ bh,
                    const float* __restrict__ Wsm, const float* __restrict__ bs,
                    float* __restrict__ Ebuf, float* __restrict__ Dbuf)
{
    __shared__ float As[16][68];   // A tile transposed: As[k][m], pad 64->68
    __shared__ float Bs[16][34];   // W tile: Bs[k][n],            pad 32->34

    const int tid = threadIdx.x;
    const int bid = blockIdx.x;
    const bool isE = (bid < 512);

    const float* Am; const float* Wm; const float* bi;
    int mb, nb;
    if (isE) { mb = (bid & 63) << 6;  nb = (bid >> 6) << 5; Am = enc; Wm = Wh;  bi = bh; }
    else     { int b2 = bid - 512; mb = (b2 & 15) << 6; nb = (b2 >> 4) << 5; Am = dec; Wm = Wsm; bi = bs; }

    const int ar = tid >> 2, ak = (tid & 3) << 2;    // A load: m-row, k-col (float4)
    const int wr = tid >> 4, wn = (tid & 15) << 1;   // W load: k-row, n-col (float2)
    const int m0 = (tid & 15) << 2, n0 = (tid >> 4) << 1;  // output 4m x 2n

    float c[4][2] = {};

    float4 av = *(const float4*)&Am[(size_t)(mb + ar) * H_ + ak];
    float2 wv = *(const float2*)&Wm[(size_t)wr * A_ + nb + wn];

    for (int k0 = 0; k0 < H_; k0 += 16) {
        __syncthreads();   // previous panel's LDS reads done
        As[ak + 0][ar] = av.x; As[ak + 1][ar] = av.y;
        As[ak + 2][ar] = av.z; As[ak + 3][ar] = av.w;
        *(float2*)&Bs[wr][wn] = wv;
        __syncthreads();
        if (k0 + 16 < H_) {   // prefetch next panel; waits land at next ds_write
            av = *(const float4*)&Am[(size_t)(mb + ar) * H_ + k0 + 16 + ak];
            wv = *(const float2*)&Wm[(size_t)(k0 + 16 + wr) * A_ + nb + wn];
        }
        #pragma unroll
        for (int kk = 0; kk < 16; ++kk) {
            float4 a4 = *(const float4*)&As[kk][m0];
            float2 b2 = *(const float2*)&Bs[kk][n0];
            c[0][0] = fmaf(a4.x, b2.x, c[0][0]); c[0][1] = fmaf(a4.x, b2.y, c[0][1]);
            c[1][0] = fmaf(a4.y, b2.x, c[1][0]); c[1][1] = fmaf(a4.y, b2.y, c[1][1]);
            c[2][0] = fmaf(a4.z, b2.x, c[2][0]); c[2][1] = fmaf(a4.z, b2.y, c[2][1]);
            c[3][0] = fmaf(a4.w, b2.x, c[3][0]); c[3][1] = fmaf(a4.w, b2.y, c[3][1]);
        }
    }

    // epilogue: e = exp(2*(c + bias)) = exp2(K2F*(c+bias))
    float2 bv2 = *(const float2*)&bi[nb + n0];
    float bb[2] = {bv2.x, bv2.y};
    float e[4][2];
    #pragma unroll
    for (int i = 0; i < 4; ++i)
        #pragma unroll
        for (int j = 0; j < 2; ++j)
            e[i][j] = ex2((c[i][j] + bb[j]) * K2F);

    if (isE) {
        // transposed store: Ebuf[b][a][s]; tile lies in one batch (64 | 1024)
        const int b = mb >> 10;
        const int s = (mb & 1023) + m0;
        #pragma unroll
        for (int j = 0; j < 2; ++j) {
            float4 v = make_float4(e[0][j], e[1][j], e[2][j], e[3][j]);
            *(float4*)&Ebuf[((size_t)b * A_ + (nb + n0 + j)) * S_ + s] = v;
        }
    } else {
        #pragma unroll
        for (int i = 0; i < 4; ++i) {
            float2 v = make_float2(e[i][0], e[i][1]);
            *(float2*)&Dbuf[(size_t)(mb + m0 + i) * A_ + nb + n0] = v;
        }
    }
}

// ---------------------------------------------------------------------------
// Kernel 2: fused score + softmax.
// block = (b, 4 t-rows); 1024 threads (16 waves), each owns ONE s column.
// score'[t][s] = -2 * sum_a Wv[a] / (E[b,a,s]*D[b,t,a] + 1)
// a-pairs share one reciprocal: w1/q1 + w2/q2 = (w1*q2 + w2*q1)*rcp(q1*q2).
// D/Wv reads are wave-uniform -> scalar-cache loads, no LDS staging.
// ---------------------------------------------------------------------------
__device__ __forceinline__ void pair_acc(float e1, float e2, float d1, float d2,
                                         float w1, float w2, float& acc)
{
    float q1  = fmaf(e1, d1, 1.0f);
    float q2  = fmaf(e2, d2, 1.0f);
    float num = fmaf(w1, q2, w2 * q1);
    acc = fmaf(num, rcpf_(q1 * q2), acc);
}

__global__ __launch_bounds__(1024)
void score_softmax(const float* __restrict__ E, const float* __restrict__ D,
                   const float* __restrict__ Wv, float* __restrict__ out)
{
    const int tid = threadIdx.x;          // = s column
    const int b  = blockIdx.x >> 6;
    const int t0 = (blockIdx.x & 63) * TT;

    __shared__ float redm[TT][16];
    __shared__ float reds[TT][16];

    const float* Eb = E + (size_t)b * A_ * S_ + tid;
    const float* Dg = D + ((size_t)b * T_ + t0) * A_;   // wave-uniform rows

    float acc[TT] = {};
    float evA[8], evB[8];
    #pragma unroll
    for (int u = 0; u < 8; ++u) evA[u] = Eb[(size_t)u * S_];

#define CHUNK8(EV, A0)                                                        \
    {                                                                         \
        float4 w0 = *(const float4*)&Wv[(A0)];                                \
        float4 w1 = *(const float4*)&Wv[(A0) + 4];                            \
        _Pragma("unroll")                                                     \
        for (int t = 0; t < TT; ++t) {                                        \
            float4 d0 = *(const float4*)&Dg[t * A_ + (A0)];                   \
            float4 d1 = *(const float4*)&Dg[t * A_ + (A0) + 4];               \
            pair_acc(EV[0], EV[1], d0.x, d0.y, w0.x, w0.y, acc[t]);           \
            pair_acc(EV[2], EV[3], d0.z, d0.w, w0.z, w0.w, acc[t]);           \
            pair_acc(EV[4], EV[5], d1.x, d1.y, w1.x, w1.y, acc[t]);           \
            pair_acc(EV[6], EV[7], d1.z, d1.w, w1.z, w1.w, acc[t]);           \
        }                                                                     \
    }

    for (int a0 = 0; a0 < A_; a0 += 16) {
        #pragma unroll
        for (int u = 0; u < 8; ++u) evB[u] = Eb[(size_t)(a0 + 8 + u) * S_];
        CHUNK8(evA, a0);
        if (a0 + 16 < A_) {
            #pragma unroll
            for (int u = 0; u < 8; ++u) evA[u] = Eb[(size_t)(a0 + 16 + u) * S_];
        }
        CHUNK8(evB, a0 + 8);
    }
#undef CHUNK8

    // ---- softmax over s (per t row), 16-wave block reduction ----
    const int lane = tid & 63, wid = tid >> 6;
    float sc[TT];
    #pragma unroll
    for (int t = 0; t < TT; ++t) sc[t] = -2.0f * acc[t];

    #pragma unroll
    for (int t = 0; t < TT; ++t) {
        float mx = sc[t];
        #pragma unroll
        for (int off = 32; off > 0; off >>= 1) mx = fmaxf(mx, __shfl_xor(mx, off, 64));
        if (lane == 0) redm[t][wid] = mx;
    }
    __syncthreads();

    float mrow[TT];
    #pragma unroll
    for (int t = 0; t < TT; ++t) {
        float m = redm[t][0];
        #pragma unroll
        for (int i = 1; i < 16; ++i) m = fmaxf(m, redm[t][i]);
        mrow[t] = m;
    }

    #pragma unroll
    for (int t = 0; t < TT; ++t) {
        sc[t] = ex2((sc[t] - mrow[t]) * LOG2EF);
        float s = sc[t];
        #pragma unroll
        for (int off = 32; off > 0; off >>= 1) s += __shfl_xor(s, off, 64);
        if (lane == 0) reds[t][wid] = s;
    }
    __syncthreads();

    #pragma unroll
    for (int t = 0; t < TT; ++t) {
        float ssum = reds[t][0];
        #pragma unroll
        for (int i = 1; i < 16; ++i) ssum += reds[t][i];
        float inv = 1.0f / ssum;
        out[((size_t)b * T_ + (t0 + t)) * S_ + tid] = sc[t] * inv;
    }
}

// ---------------------------------------------------------------------------
extern "C" void kernel_launch(void* const* d_in, const int* in_sizes, int n_in,
                              void* d_out, int out_size, void* d_ws, size_t ws_size,
                              hipStream_t stream)
{
    const float* enc = (const float*)d_in[0];
    const float* dec = (const float*)d_in[1];
    const float* Wh  = (const float*)d_in[2];
    const float* bh  = (const float*)d_in[3];
    const float* Wsm = (const float*)d_in[4];
    const float* bs  = (const float*)d_in[5];
    const float* Wv  = (const float*)d_in[6];
    // d_in[7] (bv) intentionally unused: softmax is shift-invariant.

    float* Ebuf = (float*)d_ws;                      // B*A*S floats = 4 MB
    float* Dbuf = Ebuf + (size_t)B_ * A_ * S_;       // B*T*A floats = 1 MB

    fused_gemm_exp<<<640, 256, 0, stream>>>(enc, dec, Wh, bh, Wsm, bs, Ebuf, Dbuf);
    score_softmax<<<B_ * (T_ / TT), 1024, 0, stream>>>(Ebuf, Dbuf, Wv, (float*)d_out);
}

// Round 3
// 58.369 us; speedup vs baseline: 1.3525x; 1.1967x over previous
//
#include <hip/hip_runtime.h>

// Problem dims (fixed by setup_inputs): B=4, S=1024, T=256, H=512, A=256
#define B_ 4
#define S_ 1024
#define T_ 256
#define H_ 512
#define A_ 256
#define TT 4   // t-rows per score block

typedef __attribute__((ext_vector_type(8))) short short8;   // 8 bf16 = 4 VGPR
typedef __attribute__((ext_vector_type(4))) float f32x4;    // MFMA acc

__device__ __forceinline__ float ex2(float x)   { return __builtin_amdgcn_exp2f(x); }
__device__ __forceinline__ float rcpf_(float x) { return __builtin_amdgcn_rcpf(x); }

#define K2F 2.8853900817779268f     // 2*log2(e): exp(2x) = exp2(K2F*x)
#define LOG2EF 1.4426950408889634f

// fp32 -> bf16 split: x ~= hi + lo (both bf16, RNE). Dropped lo*lo term in
// products is ~2^-18 relative -> negligible vs 1.9e-4 threshold.
__device__ __forceinline__ void split_bf16(float x, unsigned short& h, unsigned short& l)
{
    unsigned u = __float_as_uint(x);
    unsigned r = (u + 0x7FFFu + ((u >> 16) & 1u)) >> 16;
    h = (unsigned short)r;
    float hf = __uint_as_float(r << 16);
    float lo = x - hf;                       // exact in fp32
    unsigned u2 = __float_as_uint(lo);
    l = (unsigned short)((u2 + 0x7FFFu + ((u2 >> 16) & 1u)) >> 16);
}

// ---------------------------------------------------------------------------
// Kernel 0: transpose + bf16-split W matrices.  W[k][a] -> WT_hi/lo[a][k].
// 256 blocks x 256 thr; 32x32 tiles through LDS; runs once, ~1.5us.
// ---------------------------------------------------------------------------
__global__ __launch_bounds__(256)
void prep_w(const float* __restrict__ Wh, const float* __restrict__ Wsm,
            unsigned short* __restrict__ WhTh, unsigned short* __restrict__ WhTl,
            unsigned short* __restrict__ WsTh, unsigned short* __restrict__ WsTl)
{
    __shared__ float lds[32][36];
    const int tid = threadIdx.x, bid = blockIdx.x;
    const int mat = bid >> 7, rem = bid & 127;
    const int k0 = (rem & 15) * 32, a0 = (rem >> 4) * 32;
    const float* W = mat ? Wsm : Wh;
    unsigned short* Oh = mat ? WsTh : WhTh;
    unsigned short* Ol = mat ? WsTl : WhTl;

    {
        int kl = tid >> 3, a4 = (tid & 7) * 4;
        float4 v = *(const float4*)&W[(size_t)(k0 + kl) * A_ + a0 + a4];
        lds[kl][a4] = v.x; lds[kl][a4 + 1] = v.y; lds[kl][a4 + 2] = v.z; lds[kl][a4 + 3] = v.w;
    }
    __syncthreads();
    {
        int al = tid >> 3, k4 = (tid & 7) * 4;
        unsigned short h[4], l[4];
        #pragma unroll
        for (int i = 0; i < 4; ++i) split_bf16(lds[k4 + i][al], h[i], l[i]);
        size_t o = (size_t)(a0 + al) * H_ + k0 + k4;
        *(ushort4*)&Oh[o] = make_ushort4(h[0], h[1], h[2], h[3]);
        *(ushort4*)&Ol[o] = make_ushort4(l[0], l[1], l[2], l[3]);
    }
}

// ---------------------------------------------------------------------------
// Kernel 1: split-bf16 MFMA GEMM + exp epilogue.
//   blocks [0,256):   E[b][a][s] = exp(2*(enc@Wh + bh))  (transposed store)
//   blocks [256,320): D[m][a]    = exp(2*(dec@Ws + bs))  (row-major store)
// BM=64, BN=64, BK=32; 4 waves (2x2), each wave 32x32 = 2x2 frags of 16x16.
// LDS tiles in FRAGMENT-MAJOR layout: each lane's 8-bf16 operand is a
// contiguous 16B region -> ds_write_b128 and ds_read_b128 both have
// consecutive lanes on consecutive 16B = conflict-free.
// Register prefetch of next K-panel hides global latency under MFMA phase.
// ---------------------------------------------------------------------------
__global__ __launch_bounds__(256)
void gemm_mfma(const float* __restrict__ enc, const float* __restrict__ dec,
               const unsigned short* __restrict__ WhTh, const unsigned short* __restrict__ WhTl,
               const unsigned short* __restrict__ WsTh, const unsigned short* __restrict__ WsTl,
               const float* __restrict__ bh, const float* __restrict__ bs,
               float* __restrict__ Ebuf, float* __restrict__ Dbuf)
{
    __shared__ short smem[8192];          // 16 KB: Ahi|Alo|Bhi|Blo, 4KB each
    short* Ah = smem;
    short* Al = smem + 2048;
    short* Bh = smem + 4096;
    short* Bl = smem + 6144;

    const int tid = threadIdx.x, bid = blockIdx.x;
    const bool isE = bid < 256;
    int mb, nb;
    const float* Ag; const unsigned short* WTh; const unsigned short* WTl; const float* bias;
    if (isE) { mb = (bid & 63) * 64; nb = (bid >> 6) * 64; Ag = enc; WTh = WhTh; WTl = WhTl; bias = bh; }
    else { int b2 = bid - 256; mb = (b2 & 15) * 64; nb = (b2 >> 4) * 64; Ag = dec; WTh = WsTh; WTl = WsTl; bias = bs; }

    // staging map: thread t owns row m_l (n_l), k-chunk q (8 consecutive k)
    const int m_l = tid >> 2, q = tid & 3;
    const size_t arow = (size_t)(mb + m_l) * H_ + 8 * q;   // A: fp32 [m][k]
    const size_t brow = (size_t)(nb + m_l) * H_ + 8 * q;   // WT: bf16 [a][k]
    const int woff = ((m_l >> 4) * 64 + (m_l & 15) + 16 * q) * 8;  // frag-major slot (shorts)

    // frag map: wave (wm,wn) owns rows 32*wm.., cols 32*wn..
    const int wave = tid >> 6, lane = tid & 63;
    const int wm = wave >> 1, wn = wave & 1;
    const int roffA = (2 * wm) * 512 + lane * 8;   // + mf*512
    const int roffB = (2 * wn) * 512 + lane * 8;   // + nf*512

    const int cl = lane & 15, rg = lane >> 4;
    const float bias0 = bias[nb + wn * 32 + cl];
    const float bias1 = bias[nb + wn * 32 + 16 + cl];

    f32x4 acc[2][2] = {};

    float4 aA = *(const float4*)&Ag[arow];
    float4 aB = *(const float4*)&Ag[arow + 4];
    short8 bHv = *(const short8*)&WTh[brow];
    short8 bLv = *(const short8*)&WTl[brow];

    for (int it = 0; it < 16; ++it) {
        __syncthreads();                      // prev iter's frag reads done
        {
            float xs[8] = {aA.x, aA.y, aA.z, aA.w, aB.x, aB.y, aB.z, aB.w};
            short8 hv, lv;
            #pragma unroll
            for (int j = 0; j < 8; ++j) {
                unsigned short h, l; split_bf16(xs[j], h, l);
                hv[j] = (short)h; lv[j] = (short)l;
            }
            *(short8*)&Ah[woff] = hv;
            *(short8*)&Al[woff] = lv;
            *(short8*)&Bh[woff] = bHv;
            *(short8*)&Bl[woff] = bLv;
        }
        if (it < 15) {                        // prefetch next K-panel
            int kn = (it + 1) * 32;
            aA  = *(const float4*)&Ag[arow + kn];
            aB  = *(const float4*)&Ag[arow + kn + 4];
            bHv = *(const short8*)&WTh[brow + kn];
            bLv = *(const short8*)&WTl[brow + kn];
        }
        __syncthreads();
        short8 fAh0 = *(short8*)&Ah[roffA], fAh1 = *(short8*)&Ah[roffA + 512];
        short8 fAl0 = *(short8*)&Al[roffA], fAl1 = *(short8*)&Al[roffA + 512];
        short8 fBh0 = *(short8*)&Bh[roffB], fBh1 = *(short8*)&Bh[roffB + 512];
        short8 fBl0 = *(short8*)&Bl[roffB], fBl1 = *(short8*)&Bl[roffB + 512];
        // hi*hi + hi*lo + lo*hi per (mf,nf), chained into same acc
        acc[0][0] = __builtin_amdgcn_mfma_f32_16x16x32_bf16(fAh0, fBh0, acc[0][0], 0, 0, 0);
        acc[0][0] = __builtin_amdgcn_mfma_f32_16x16x32_bf16(fAh0, fBl0, acc[0][0], 0, 0, 0);
        acc[0][0] = __builtin_amdgcn_mfma_f32_16x16x32_bf16(fAl0, fBh0, acc[0][0], 0, 0, 0);
        acc[0][1] = __builtin_amdgcn_mfma_f32_16x16x32_bf16(fAh0, fBh1, acc[0][1], 0, 0, 0);
        acc[0][1] = __builtin_amdgcn_mfma_f32_16x16x32_bf16(fAh0, fBl1, acc[0][1], 0, 0, 0);
        acc[0][1] = __builtin_amdgcn_mfma_f32_16x16x32_bf16(fAl0, fBh1, acc[0][1], 0, 0, 0);
        acc[1][0] = __builtin_amdgcn_mfma_f32_16x16x32_bf16(fAh1, fBh0, acc[1][0], 0, 0, 0);
        acc[1][0] = __builtin_amdgcn_mfma_f32_16x16x32_bf16(fAh1, fBl0, acc[1][0], 0, 0, 0);
        acc[1][0] = __builtin_amdgcn_mfma_f32_16x16x32_bf16(fAl1, fBh0, acc[1][0], 0, 0, 0);
        acc[1][1] = __builtin_amdgcn_mfma_f32_16x16x32_bf16(fAh1, fBh1, acc[1][1], 0, 0, 0);
        acc[1][1] = __builtin_amdgcn_mfma_f32_16x16x32_bf16(fAh1, fBl1, acc[1][1], 0, 0, 0);
        acc[1][1] = __builtin_amdgcn_mfma_f32_16x16x32_bf16(fAl1, fBh1, acc[1][1], 0, 0, 0);
    }

    // epilogue: exp2(K2F*(acc+bias)); C/D layout: col=lane&15, row=4*(lane>>4)+reg
    #pragma unroll
    for (int mf = 0; mf < 2; ++mf) {
        const int mg = mb + wm * 32 + mf * 16 + rg * 4;
        #pragma unroll
        for (int nf = 0; nf < 2; ++nf) {
            const int a = nb + wn * 32 + nf * 16 + cl;
            const float bb = nf ? bias1 : bias0;
            f32x4 ac = acc[mf][nf];
            float4 st;
            st.x = ex2((ac[0] + bb) * K2F);
            st.y = ex2((ac[1] + bb) * K2F);
            st.z = ex2((ac[2] + bb) * K2F);
            st.w = ex2((ac[3] + bb) * K2F);
            if (isE) {
                const int b = mg >> 10, s = mg & 1023;   // frag rows = 4 consecutive s
                *(float4*)&Ebuf[(((size_t)b * A_ + a) << 10) + s] = st;
            } else {
                Dbuf[(size_t)(mg + 0) * A_ + a] = st.x;
                Dbuf[(size_t)(mg + 1) * A_ + a] = st.y;
                Dbuf[(size_t)(mg + 2) * A_ + a] = st.z;
                Dbuf[(size_t)(mg + 3) * A_ + a] = st.w;
            }
        }
    }
}

// ---------------------------------------------------------------------------
// Kernel 2: fused score + softmax (unchanged from round 2, known-good).
// block = (b, 4 t-rows); 1024 threads, each owns ONE s column.
// score'[t][s] = -2 * sum_a Wv[a] / (E[b,a,s]*D[b,t,a] + 1)
// ---------------------------------------------------------------------------
__device__ __forceinline__ void pair_acc(float e1, float e2, float d1, float d2,
                                         float w1, float w2, float& acc)
{
    float q1  = fmaf(e1, d1, 1.0f);
    float q2  = fmaf(e2, d2, 1.0f);
    float num = fmaf(w1, q2, w2 * q1);
    acc = fmaf(num, rcpf_(q1 * q2), acc);
}

__global__ __launch_bounds__(1024)
void score_softmax(const float* __restrict__ E, const float* __restrict__ D,
                   const float* __restrict__ Wv, float* __restrict__ out)
{
    const int tid = threadIdx.x;          // = s column
    const int b  = blockIdx.x >> 6;
    const int t0 = (blockIdx.x & 63) * TT;

    __shared__ float redm[TT][16];
    __shared__ float reds[TT][16];

    const float* Eb = E + (size_t)b * A_ * S_ + tid;
    const float* Dg = D + ((size_t)b * T_ + t0) * A_;   // wave-uniform rows

    float acc[TT] = {};
    float evA[8], evB[8];
    #pragma unroll
    for (int u = 0; u < 8; ++u) evA[u] = Eb[(size_t)u * S_];

#define CHUNK8(EV, A0)                                                        \
    {                                                                         \
        float4 w0 = *(const float4*)&Wv[(A0)];                                \
        float4 w1 = *(const float4*)&Wv[(A0) + 4];                            \
        _Pragma("unroll")                                                     \
        for (int t = 0; t < TT; ++t) {                                        \
            float4 d0 = *(const float4*)&Dg[t * A_ + (A0)];                   \
            float4 d1 = *(const float4*)&Dg[t * A_ + (A0) + 4];               \
            pair_acc(EV[0], EV[1], d0.x, d0.y, w0.x, w0.y, acc[t]);           \
            pair_acc(EV[2], EV[3], d0.z, d0.w, w0.z, w0.w, acc[t]);           \
            pair_acc(EV[4], EV[5], d1.x, d1.y, w1.x, w1.y, acc[t]);           \
            pair_acc(EV[6], EV[7], d1.z, d1.w, w1.z, w1.w, acc[t]);           \
        }                                                                     \
    }

    for (int a0 = 0; a0 < A_; a0 += 16) {
        #pragma unroll
        for (int u = 0; u < 8; ++u) evB[u] = Eb[(size_t)(a0 + 8 + u) * S_];
        CHUNK8(evA, a0);
        if (a0 + 16 < A_) {
            #pragma unroll
            for (int u = 0; u < 8; ++u) evA[u] = Eb[(size_t)(a0 + 16 + u) * S_];
        }
        CHUNK8(evB, a0 + 8);
    }
#undef CHUNK8

    // ---- softmax over s (per t row), 16-wave block reduction ----
    const int lane = tid & 63, wid = tid >> 6;
    float sc[TT];
    #pragma unroll
    for (int t = 0; t < TT; ++t) sc[t] = -2.0f * acc[t];

    #pragma unroll
    for (int t = 0; t < TT; ++t) {
        float mx = sc[t];
        #pragma unroll
        for (int off = 32; off > 0; off >>= 1) mx = fmaxf(mx, __shfl_xor(mx, off, 64));
        if (lane == 0) redm[t][wid] = mx;
    }
    __syncthreads();

    float mrow[TT];
    #pragma unroll
    for (int t = 0; t < TT; ++t) {
        float m = redm[t][0];
        #pragma unroll
        for (int i = 1; i < 16; ++i) m = fmaxf(m, redm[t][i]);
        mrow[t] = m;
    }

    #pragma unroll
    for (int t = 0; t < TT; ++t) {
        sc[t] = ex2((sc[t] - mrow[t]) * LOG2EF);
        float s = sc[t];
        #pragma unroll
        for (int off = 32; off > 0; off >>= 1) s += __shfl_xor(s, off, 64);
        if (lane == 0) reds[t][wid] = s;
    }
    __syncthreads();

    #pragma unroll
    for (int t = 0; t < TT; ++t) {
        float ssum = reds[t][0];
        #pragma unroll
        for (int i = 1; i < 16; ++i) ssum += reds[t][i];
        float inv = 1.0f / ssum;
        out[((size_t)b * T_ + (t0 + t)) * S_ + tid] = sc[t] * inv;
    }
}

// ---------------------------------------------------------------------------
extern "C" void kernel_launch(void* const* d_in, const int* in_sizes, int n_in,
                              void* d_out, int out_size, void* d_ws, size_t ws_size,
                              hipStream_t stream)
{
    const float* enc = (const float*)d_in[0];
    const float* dec = (const float*)d_in[1];
    const float* Wh  = (const float*)d_in[2];
    const float* bh  = (const float*)d_in[3];
    const float* Wsm = (const float*)d_in[4];
    const float* bs  = (const float*)d_in[5];
    const float* Wv  = (const float*)d_in[6];
    // d_in[7] (bv) intentionally unused: softmax is shift-invariant.

    float* Ebuf = (float*)d_ws;                              // 1M floats (4 MB)
    float* Dbuf = Ebuf + (size_t)B_ * A_ * S_;               // 256K floats (1 MB)
    unsigned short* wt = (unsigned short*)(Dbuf + (size_t)B_ * T_ * A_);
    unsigned short* WhTh = wt;                               // 256x512 bf16 each
    unsigned short* WhTl = wt + 131072;
    unsigned short* WsTh = wt + 262144;
    unsigned short* WsTl = wt + 393216;

    prep_w<<<256, 256, 0, stream>>>(Wh, Wsm, WhTh, WhTl, WsTh, WsTl);
    gemm_mfma<<<320, 256, 0, stream>>>(enc, dec, WhTh, WhTl, WsTh, WsTl,
                                       bh, bs, Ebuf, Dbuf);
    score_softmax<<<B_ * (T_ / TT), 1024, 0, stream>>>(Ebuf, Dbuf, Wv, (float*)d_out);
}